// Round 1
// baseline (719.856 us; speedup 1.0000x reference)
//
#include <hip/hip_runtime.h>

typedef _Float16 f16;
typedef _Float16 f16x8 __attribute__((ext_vector_type(8)));
typedef _Float16 f16x4 __attribute__((ext_vector_type(4)));
typedef float f32x4 __attribute__((ext_vector_type(4)));

#define NCAM 6
#define CINF 512
#define MIDC 256
#define DB   112
#define HH   32
#define WW   88
#define PH   34
#define PW   90
#define NPOS (HH*WW)       /* 2816 */
#define PTILE 64
#define PT_PER_CAM 44      /* 2816/64 */

// ---- workspace layout (bytes) ----
#define O_GATE   0L
#define O_WFRED  6144L
#define O_LOG    6144L        /* overlays WfRed+WfBB; written only after all f16 convs done */
#define O_WFBB   2365440L
#define O_WFDP   9443328L
#define O_XP0    9508864L
#define O_X1     28309504L
#define O_DP     28309504L    /* overlays X1; written only after X1's last read */
#define O_X2     37709824L
#define O_X3     47110144L
/* end: 56510464 (< 71.6MB known-good ws) */

__device__ __forceinline__ void gl_lds16(const void* g, void* l) {
  __builtin_amdgcn_global_load_lds((const __attribute__((address_space(1))) void*)g,
                                   (__attribute__((address_space(3))) void*)l, 16, 0, 0);
}

// ---------------- halo-only zeroing of the 4 padded NHWC buffers ----------------
__global__ void halo_zero_kernel(f16* __restrict__ xp0, f16* __restrict__ X1,
                                 f16* __restrict__ X2, f16* __restrict__ X3) {
  int idx = blockIdx.x * 256 + threadIdx.x;       // one 16B chunk each
  f16* base; int C, rem;
  if (idx < 93696) { base = xp0; C = 512; rem = idx; }
  else {
    int k = idx - 93696;
    int bsel = k / 46848;
    if (bsel >= 3) return;
    rem = k - bsel * 46848; C = 256;
    base = (bsel == 0) ? X1 : (bsel == 1) ? X2 : X3;
  }
  int chunks = C >> 3;
  int cell = rem / chunks, cc = rem - cell * chunks;
  int cam = cell / 244, p = cell - cam * 244;
  int hh, ww;
  if (p < 90)       { hh = 0;  ww = p; }
  else if (p < 180) { hh = 33; ww = p - 90; }
  else { int q = p - 180; hh = 1 + (q >> 1); ww = (q & 1) * 89; }
  long o = ((long)(cam * PH + hh) * PW + ww) * C + cc * 8;
  f16x8 z = {0,0,0,0,0,0,0,0};
  *(f16x8*)(base + o) = z;
}

// ---------------- weights -> MFMA A-fragment order, scale folded ----------------
// dst idx = (((g*TAPS+tap)*KST+ks)<<11) + (mi<<9) + (lane<<3) + j
// co = g*64+mi*16+(lane&15), ci = ks*32+(lane>>4)*8+j, src OIHW[co][ci][tap]
__global__ void wfrag_kernel(const float* __restrict__ src, const float* __restrict__ scale,
                             f16* __restrict__ dst, int NC, int G, int TAPS, int CI, int CO_SRC,
                             long per, long total) {
  long i = (long)blockIdx.x * blockDim.x + threadIdx.x;
  long stride = (long)gridDim.x * blockDim.x;
  int KST = CI >> 5;
  for (; i < total; i += stride) {
    int conv = (int)(i / per);
    long rem = i - (long)conv * per;
    int j = (int)(rem & 7);
    int lane = (int)((rem >> 3) & 63);
    int mi = (int)((rem >> 9) & 3);
    long b = rem >> 11;
    int ks = (int)(b % KST);
    long b2 = b / KST;
    int tap = (int)(b2 % TAPS);
    int g = (int)(b2 / TAPS);
    int co = g * 64 + mi * 16 + (lane & 15);
    int ci = ks * 32 + (lane >> 4) * 8 + j;
    float v = 0.f;
    if (co < CO_SRC) {
      v = src[(long)conv * CO_SRC * CI * TAPS + ((long)co * CI + ci) * TAPS + tap];
      if (scale) v *= scale[conv * CO_SRC + co];
    }
    dst[i] = (f16)v;
  }
}

// ---------------- img NCHW f32 -> padded NHWC f16 ----------------
__global__ void img_trans_kernel(const float* __restrict__ src, f16* __restrict__ dst) {
  __shared__ float tile[32][33];
  int tx = threadIdx.x & 31, ty = threadIdx.x >> 5;
  int wt = blockIdx.x % 3, ct = blockIdx.x / 3;
  int h = blockIdx.y, n = blockIdx.z;
  int w0 = wt * 32, c0 = ct * 32;
  #pragma unroll
  for (int i = 0; i < 4; ++i) {
    int cl = ty + i * 8;
    int w = w0 + tx;
    float v = 0.f;
    if (w < WW) v = src[((long)(n * CINF + c0 + cl) * HH + h) * WW + w];
    tile[cl][tx] = v;
  }
  __syncthreads();
  #pragma unroll
  for (int i = 0; i < 4; ++i) {
    int wl = ty + i * 8;
    int w = w0 + wl;
    if (w < WW)
      dst[((long)((n * PH + h + 1) * PW + (w + 1))) * CINF + c0 + tx] = (f16)tile[tx][wl];
  }
}

// ---------------- SE gate ----------------
__global__ void se_gate_kernel(const float* __restrict__ intr,
                               const float* __restrict__ w1, const float* __restrict__ b1,
                               const float* __restrict__ w2, const float* __restrict__ b2,
                               const float* __restrict__ rw, const float* __restrict__ rb,
                               const float* __restrict__ ew, const float* __restrict__ eb,
                               float* __restrict__ gate) {
  __shared__ float sps;
  __shared__ float h1[MIDC];
  __shared__ float h2[MIDC];
  __shared__ float tt[MIDC];
  int n = blockIdx.x, c = threadIdx.x;
  if (c == 0) {
    float a[4][8];
    for (int i = 0; i < 4; ++i)
      for (int j = 0; j < 4; ++j) {
        a[i][j] = intr[n * 16 + i * 4 + j];
        a[i][4 + j] = (i == j) ? 1.f : 0.f;
      }
    for (int col = 0; col < 4; ++col) {
      int piv = col;
      for (int r2 = col + 1; r2 < 4; ++r2)
        if (fabsf(a[r2][col]) > fabsf(a[piv][col])) piv = r2;
      if (piv != col)
        for (int j = 0; j < 8; ++j) { float tv = a[col][j]; a[col][j] = a[piv][j]; a[piv][j] = tv; }
      float invp = 1.f / a[col][col];
      for (int j = 0; j < 8; ++j) a[col][j] *= invp;
      for (int r2 = 0; r2 < 4; ++r2)
        if (r2 != col) {
          float f = a[r2][col];
          for (int j = 0; j < 8; ++j) a[r2][j] -= f * a[col][j];
        }
    }
    float i00 = a[0][4], i11 = a[1][5];
    sps = sqrtf(i00 * i00 + i11 * i11) * 1000.f;
  }
  __syncthreads();
  float sp = sps;
  h1[c] = fmaxf(sp * w1[c] + b1[c], 0.f);
  __syncthreads();
  float acc = b2[c];
  for (int j = 0; j < MIDC; ++j) acc += h1[j] * w2[j * MIDC + c];
  h2[c] = acc;
  __syncthreads();
  acc = rb[c];
  for (int j = 0; j < MIDC; ++j) acc += rw[c * MIDC + j] * h2[j];
  tt[c] = fmaxf(acc, 0.f);
  __syncthreads();
  acc = eb[c];
  for (int j = 0; j < MIDC; ++j) acc += ew[c * MIDC + j] * tt[j];
  gate[n * MIDC + c] = 1.f / (1.f + expf(-acc));
}

// ---------------- MFMA implicit-GEMM conv, m97-style K-loop ----------------
// Tile 128co x 64pos, 4 waves (2x2), wave 64co x 32pos. B via global_load_lds
// (XOR-swizzled), A streamed from pre-fragmented weights straight to VGPRs,
// reg-double-buffered. Grid 528 (2 co_tiles) -> ~2 independent blocks/CU so one
// block's barrier drain overlaps the other's MFMA (m97 mechanism).
// MODE 0: relu(acc+b)*gate   MODE 1: relu(acc+b)   MODE 2: relu(acc+b+res)   MODE 3: acc+b -> f32
template<int MODE, int CIN_T, int TAPS>
__global__ __launch_bounds__(256, 4)
void conv_mfma(const f16* __restrict__ X, const f16* __restrict__ Wf,
               const float* __restrict__ bias, const float* __restrict__ gate,
               const f16* __restrict__ res, f16* __restrict__ Yf16,
               float* __restrict__ Yf32, int co_tiles) {
  constexpr int KST = CIN_T / 32;
  constexpr int CPT = CIN_T / 64;
  constexpr int NCH = TAPS * CPT;
  constexpr int LCPT = (CPT == 8) ? 3 : 2;
  __shared__ __align__(16) f16 Bs[8192];   // 2 x 8KB

  const int t = threadIdx.x;
  const int wv = t >> 6, ln = t & 63, lm = ln & 15, quad = ln >> 4;
  const int wm = wv >> 1, wn = wv & 1;
  const int bid = blockIdx.x;
  const int co_tile = bid % co_tiles;
  const int ptile = bid / co_tiles;
  const int cam = ptile / PT_PER_CAM;
  const int pbase = (ptile % PT_PER_CAM) * PTILE;

  // B DMA setup: 2 instrs/wave, each covers 8 rows x 8 phys chunks
  const f16* gB[2]; int ldsoff[2];
  const int clog = (ln & 7) ^ (ln >> 3);
  #pragma unroll
  for (int j = 0; j < 2; ++j) {
    int reg = j * 4 + wv;
    int r = reg * 8 + (ln >> 3);
    int pos = pbase + r;
    int hh = pos / WW, w2 = pos - hh * WW;
    gB[j] = X + ((long)((cam * PH + hh + 1) * PW + (w2 + 1))) * CIN_T + clog * 8;
    ldsoff[j] = reg * 1024;
  }
  // A stream pointer for this wave's 64-co group
  const int g = co_tile * 2 + wm;
  const f16* wa = Wf + (long)g * TAPS * KST * 2048 + ln * 8;

  // lane-constant bf addressing (bytes)
  const int base_l = (wn * 32 + lm) * 128;
  const int sx0 = ((0 * 4 + quad) ^ (lm & 7)) * 16;
  const int sx1 = ((1 * 4 + quad) ^ (lm & 7)) * 16;

  f32x4 acc[4][2];
  #pragma unroll
  for (int mi = 0; mi < 4; ++mi)
    #pragma unroll
    for (int ni = 0; ni < 2; ++ni)
      #pragma unroll
      for (int r = 0; r < 4; ++r) acc[mi][ni][r] = 0.f;

  auto choff = [&](int c) -> long {
    long off = 0;
    if (TAPS == 9) {
      int tp = c >> LCPT;
      int dy = tp / 3 - 1, dx = tp % 3 - 1;
      off = (long)(dy * PW + dx) * CIN_T;
    }
    return off + (long)(c & (CPT - 1)) * 64;
  };
  auto dmaf = [&](int bsel, long curf) {
    #pragma unroll
    for (int j = 0; j < 2; ++j)
      gl_lds16(gB[j] + curf, (char*)Bs + bsel * 8192 + ldsoff[j]);
  };
  auto load_af = [&](f16x8* af, int c) {
    const f16* p = wa + (long)c * 4096;
    #pragma unroll
    for (int s = 0; s < 2; ++s)
      #pragma unroll
      for (int mi = 0; mi < 4; ++mi)
        af[s * 4 + mi] = *(const f16x8*)(p + s * 2048 + mi * 512);
  };
  auto compute = [&](int bsel, const f16x8* af) {
    const char* bb = (const char*)Bs + bsel * 8192 + base_l;
    #pragma unroll
    for (int s = 0; s < 2; ++s) {
      f16x8 bf[2];
      int sx = s ? sx1 : sx0;
      #pragma unroll
      for (int ni = 0; ni < 2; ++ni)
        bf[ni] = *(const f16x8*)(bb + ni * 2048 + sx);
      #pragma unroll
      for (int mi = 0; mi < 4; ++mi)
        #pragma unroll
        for (int ni = 0; ni < 2; ++ni)
          acc[mi][ni] = __builtin_amdgcn_mfma_f32_16x16x32_f16(af[s * 4 + mi], bf[ni], acc[mi][ni], 0, 0, 0);
    }
  };

  f16x8 afA[8], afB[8];
  dmaf(0, choff(0));
  load_af(afA, 0);
  __syncthreads();

  #pragma unroll 1
  for (int c = 0; c < NCH; c += 2) {
    dmaf(1, choff(c + 1));
    load_af(afB, c + 1);
    compute(0, afA);
    __syncthreads();
    if (c + 2 < NCH) { dmaf(0, choff(c + 2)); load_af(afA, c + 2); }
    compute(1, afB);
    __syncthreads();
  }

  // ---- epilogue: direct stores from acc ----
  float4 b4[4], g4[4];
  bool skip[4];
  #pragma unroll
  for (int mi = 0; mi < 4; ++mi) {
    int co_l = wm * 64 + mi * 16 + quad * 4;
    int co_g = co_tile * 128 + co_l;
    skip[mi] = (MODE == 3) && (co_l >= DB);
    if (!skip[mi]) b4[mi] = *(const float4*)(bias + co_g);
    if (MODE == 0) g4[mi] = *(const float4*)(gate + cam * MIDC + co_g);
  }
  #pragma unroll
  for (int ni = 0; ni < 2; ++ni) {
    int pos = pbase + wn * 32 + ni * 16 + lm;
    long ob;
    if (MODE == 3) ob = ((long)(cam * NPOS + pos)) * DB;
    else {
      int hh = pos / WW, w2 = pos - hh * WW;
      ob = ((long)((cam * PH + hh + 1) * PW + (w2 + 1))) * MIDC + co_tile * 128;
    }
    #pragma unroll
    for (int mi = 0; mi < 4; ++mi) {
      if (skip[mi]) continue;
      int co_l = wm * 64 + mi * 16 + quad * 4;
      float v[4];
      #pragma unroll
      for (int r = 0; r < 4; ++r) {
        float y = acc[mi][ni][r];
        y += ((float*)&b4[mi])[r];
        if (MODE == 0) y = fmaxf(y, 0.f) * ((float*)&g4[mi])[r];
        else if (MODE == 1) y = fmaxf(y, 0.f);
        v[r] = y;
      }
      if (MODE == 3) {
        float4 o; o.x = v[0]; o.y = v[1]; o.z = v[2]; o.w = v[3];
        *(float4*)(Yf32 + ob + co_l) = o;
      } else if (MODE == 2) {
        f16x4 rv = *(const f16x4*)(res + ob + co_l);
        f16x4 o;
        #pragma unroll
        for (int r = 0; r < 4; ++r) o[r] = (f16)fmaxf(v[r] + (float)rv[r], 0.f);
        *(f16x4*)(Yf16 + ob + co_l) = o;
      } else {
        f16x4 o;
        #pragma unroll
        for (int r = 0; r < 4; ++r) o[r] = (f16)v[r];
        *(f16x4*)(Yf16 + ob + co_l) = o;
      }
    }
  }
}

// ---------------- softmax over 112 bins, one wave per position ----------------
__global__ void softmax_kernel(const float* __restrict__ L, float* __restrict__ dp) {
  int wid = (int)(((long)blockIdx.x * blockDim.x + threadIdx.x) >> 6);
  int lane = threadIdx.x & 63;
  if (wid >= NCAM * NPOS) return;
  const float* lp = L + (long)wid * DB;
  float v0 = -1e30f, v1 = -1e30f;
  if (lane < 56) { v0 = lp[lane * 2]; v1 = lp[lane * 2 + 1]; }
  float m = fmaxf(v0, v1);
  #pragma unroll
  for (int o = 32; o; o >>= 1) m = fmaxf(m, __shfl_xor(m, o));
  float e0 = 0.f, e1 = 0.f;
  if (lane < 56) { e0 = __expf(v0 - m); e1 = __expf(v1 - m); }
  float ssum = e0 + e1;
  #pragma unroll
  for (int o = 32; o; o >>= 1) ssum += __shfl_xor(ssum, o);
  float inv = 1.f / ssum;
  if (lane < 56) {
    float2 r; r.x = e0 * inv; r.y = e1 * inv;
    *(float2*)(dp + (long)wid * DB + lane * 2) = r;
  }
}

// ---------------- trilinear grid sample + camera sum + normalize ----------------
__global__ void sample_kernel(const float* __restrict__ grid, const float* __restrict__ dp,
                              float* __restrict__ out) {
  int v = blockIdx.x * blockDim.x + threadIdx.x;
  if (v >= 128 * 128 * 16) return;
  int vz = v & 15, vy = (v >> 4) & 127, vx = v >> 11;
  float agg = 0.f, msk = 0.f;
  #pragma unroll 1
  for (int n = 0; n < NCAM; ++n) {
    long gb = ((long)((n * 128 + vx) * 128 + vy) * 16 + vz) * 3;
    float gx = grid[gb], gy = grid[gb + 1], gz = grid[gb + 2];
    float ix = ((gx + 1.f) * (float)WW - 1.f) * 0.5f;
    float iy = ((gy + 1.f) * (float)HH - 1.f) * 0.5f;
    float iz = ((gz + 1.f) * (float)DB - 1.f) * 0.5f;
    float xf = floorf(ix), yf = floorf(iy), zf = floorf(iz);
    float fx = ix - xf, fy = iy - yf, fz = iz - zf;
    int x0 = (int)xf, y0 = (int)yf, z0 = (int)zf;
    float wxa[2] = {1.f - fx, fx};
    float wya[2] = {1.f - fy, fy};
    float wza[2] = {1.f - fz, fz};
    #pragma unroll
    for (int dy2 = 0; dy2 < 2; ++dy2) {
      int y = y0 + dy2;
      bool vyb = (y >= 0) && (y < HH);
      int yc = y < 0 ? 0 : (y > HH - 1 ? HH - 1 : y);
      #pragma unroll
      for (int dx2 = 0; dx2 < 2; ++dx2) {
        int x = x0 + dx2;
        bool vxb = (x >= 0) && (x < WW);
        int xc = x < 0 ? 0 : (x > WW - 1 ? WW - 1 : x);
        float wxy = wxa[dx2] * wya[dy2];
        const float* base = dp + ((long)((n * HH + yc) * WW + xc)) * DB;
        #pragma unroll
        for (int dz2 = 0; dz2 < 2; ++dz2) {
          int z = z0 + dz2;
          bool vzb = (z >= 0) && (z < DB);
          int zc = z < 0 ? 0 : (z > DB - 1 ? DB - 1 : z);
          float wgt = wxy * wza[dz2];
          if (vxb && vyb && vzb) {
            msk += wgt;
            agg += wgt * base[zc];
          }
        }
      }
    }
  }
  out[v] = (msk > 0.f) ? (agg / msk) : agg;
}

extern "C" void kernel_launch(void* const* d_in, const int* in_sizes, int n_in,
                              void* d_out, int out_size, void* d_ws, size_t ws_size,
                              hipStream_t stream) {
  const float* img   = (const float*)d_in[0];
  const float* intr  = (const float*)d_in[1];
  const float* grid  = (const float*)d_in[2];
  const float* red_w = (const float*)d_in[3];
  const float* red_s = (const float*)d_in[4];
  const float* red_b = (const float*)d_in[5];
  const float* w1    = (const float*)d_in[6];
  const float* b1    = (const float*)d_in[7];
  const float* w2    = (const float*)d_in[8];
  const float* b2    = (const float*)d_in[9];
  const float* rw    = (const float*)d_in[10];
  const float* rb    = (const float*)d_in[11];
  const float* ew    = (const float*)d_in[12];
  const float* eb    = (const float*)d_in[13];
  const float* bb_w  = (const float*)d_in[14];
  const float* bb_s  = (const float*)d_in[15];
  const float* bb_b  = (const float*)d_in[16];
  const float* dp_w  = (const float*)d_in[17];
  const float* dp_b  = (const float*)d_in[18];
  float* out = (float*)d_out;

  char* ws = (char*)d_ws;
  float* gate = (float*)(ws + O_GATE);
  f16* wfred  = (f16*)(ws + O_WFRED);
  f16* wfbb   = (f16*)(ws + O_WFBB);
  f16* wfdp   = (f16*)(ws + O_WFDP);
  f16* xp0    = (f16*)(ws + O_XP0);
  f16* X1     = (f16*)(ws + O_X1);
  f16* X2     = (f16*)(ws + O_X2);
  f16* X3     = (f16*)(ws + O_X3);
  float* Lg   = (float*)(ws + O_LOG);
  float* dpb  = (float*)(ws + O_DP);

  halo_zero_kernel<<<915, 256, 0, stream>>>(xp0, X1, X2, X3);
  {
    long per = 4L * 9 * 16 * 2048, total = per;
    wfrag_kernel<<<2048, 256, 0, stream>>>(red_w, red_s, wfred, 1, 4, 9, 512, 256, per, total);
  }
  {
    long per = 4L * 9 * 8 * 2048, total = 6 * per;
    wfrag_kernel<<<4096, 256, 0, stream>>>(bb_w, bb_s, wfbb, 6, 4, 9, 256, 256, per, total);
  }
  {
    long per = 2L * 1 * 8 * 2048, total = per;
    wfrag_kernel<<<128, 256, 0, stream>>>(dp_w, nullptr, wfdp, 1, 2, 1, 256, 112, per, total);
  }
  img_trans_kernel<<<dim3(48, 32, 6), 256, 0, stream>>>(img, xp0);
  se_gate_kernel<<<6, 256, 0, stream>>>(intr, w1, b1, w2, b2, rw, rb, ew, eb, gate);

  const long WCH = 4L * 9 * 8 * 2048;  // per-conv fragment-weight stride (f16)

  conv_mfma<0, 512, 9><<<528, 256, 0, stream>>>(xp0, wfred, red_b, gate, nullptr, X1, nullptr, 2);

  conv_mfma<1, 256, 9><<<528, 256, 0, stream>>>(X1, wfbb + 0 * WCH, bb_b + 0 * 256, nullptr, nullptr, X2, nullptr, 2);
  conv_mfma<2, 256, 9><<<528, 256, 0, stream>>>(X2, wfbb + 1 * WCH, bb_b + 1 * 256, nullptr, X1, X3, nullptr, 2);
  conv_mfma<1, 256, 9><<<528, 256, 0, stream>>>(X3, wfbb + 2 * WCH, bb_b + 2 * 256, nullptr, nullptr, X2, nullptr, 2);
  conv_mfma<2, 256, 9><<<528, 256, 0, stream>>>(X2, wfbb + 3 * WCH, bb_b + 3 * 256, nullptr, X3, X1, nullptr, 2);
  conv_mfma<1, 256, 9><<<528, 256, 0, stream>>>(X1, wfbb + 4 * WCH, bb_b + 4 * 256, nullptr, nullptr, X2, nullptr, 2);
  conv_mfma<2, 256, 9><<<528, 256, 0, stream>>>(X2, wfbb + 5 * WCH, bb_b + 5 * 256, nullptr, X1, X3, nullptr, 2);

  conv_mfma<3, 256, 1><<<264, 256, 0, stream>>>(X3, wfdp, dp_b, nullptr, nullptr, nullptr, Lg, 1);

  softmax_kernel<<<4224, 256, 0, stream>>>(Lg, dpb);
  sample_kernel<<<1024, 256, 0, stream>>>(grid, dpb, out);
}

// Round 2
// 482.784 us; speedup vs baseline: 1.4911x; 1.4911x over previous
//
#include <hip/hip_runtime.h>

typedef _Float16 f16;
typedef _Float16 f16x8 __attribute__((ext_vector_type(8)));
typedef _Float16 f16x4 __attribute__((ext_vector_type(4)));
typedef float f32x4 __attribute__((ext_vector_type(4)));

#define NCAM 6
#define CINF 512
#define MIDC 256
#define DB   112
#define HH   32
#define WW   88
#define PH   34
#define PW   90
#define NPOS (HH*WW)       /* 2816 */
#define PTILE 64
#define PT_PER_CAM 44      /* 2816/64 */

// ---- workspace layout (bytes) ----
#define O_GATE   0L
#define O_WFRED  6144L
#define O_LOG    6144L        /* overlays WfRed+WfBB; written only after all f16 convs done */
#define O_WFBB   2365440L
#define O_WFDP   9443328L
#define O_XP0    9508864L
#define O_X1     28309504L
#define O_DP     28309504L    /* overlays X1; written only after X1's last read */
#define O_X2     37709824L
#define O_X3     47110144L
/* end: 56510464 (< 71.6MB known-good ws) */

__device__ __forceinline__ void gl_lds16(const void* g, void* l) {
  __builtin_amdgcn_global_load_lds((const __attribute__((address_space(1))) void*)g,
                                   (__attribute__((address_space(3))) void*)l, 16, 0, 0);
}

// ---------------- halo-only zeroing of the 4 padded NHWC buffers ----------------
__global__ void halo_zero_kernel(f16* __restrict__ xp0, f16* __restrict__ X1,
                                 f16* __restrict__ X2, f16* __restrict__ X3) {
  int idx = blockIdx.x * 256 + threadIdx.x;       // one 16B chunk each
  f16* base; int C, rem;
  if (idx < 93696) { base = xp0; C = 512; rem = idx; }
  else {
    int k = idx - 93696;
    int bsel = k / 46848;
    if (bsel >= 3) return;
    rem = k - bsel * 46848; C = 256;
    base = (bsel == 0) ? X1 : (bsel == 1) ? X2 : X3;
  }
  int chunks = C >> 3;
  int cell = rem / chunks, cc = rem - cell * chunks;
  int cam = cell / 244, p = cell - cam * 244;
  int hh, ww;
  if (p < 90)       { hh = 0;  ww = p; }
  else if (p < 180) { hh = 33; ww = p - 90; }
  else { int q = p - 180; hh = 1 + (q >> 1); ww = (q & 1) * 89; }
  long o = ((long)(cam * PH + hh) * PW + ww) * C + cc * 8;
  f16x8 z = {0,0,0,0,0,0,0,0};
  *(f16x8*)(base + o) = z;
}

// ---------------- weights -> MFMA A-fragment order, scale folded ----------------
// dst idx = (((g*TAPS+tap)*KST+ks)<<11) + (mi<<9) + (lane<<3) + j
// co = g*64+mi*16+(lane&15), ci = ks*32+(lane>>4)*8+j, src OIHW[co][ci][tap]
__global__ void wfrag_kernel(const float* __restrict__ src, const float* __restrict__ scale,
                             f16* __restrict__ dst, int NC, int G, int TAPS, int CI, int CO_SRC,
                             long per, long total) {
  long i = (long)blockIdx.x * blockDim.x + threadIdx.x;
  long stride = (long)gridDim.x * blockDim.x;
  int KST = CI >> 5;
  for (; i < total; i += stride) {
    int conv = (int)(i / per);
    long rem = i - (long)conv * per;
    int j = (int)(rem & 7);
    int lane = (int)((rem >> 3) & 63);
    int mi = (int)((rem >> 9) & 3);
    long b = rem >> 11;
    int ks = (int)(b % KST);
    long b2 = b / KST;
    int tap = (int)(b2 % TAPS);
    int g = (int)(b2 / TAPS);
    int co = g * 64 + mi * 16 + (lane & 15);
    int ci = ks * 32 + (lane >> 4) * 8 + j;
    float v = 0.f;
    if (co < CO_SRC) {
      v = src[(long)conv * CO_SRC * CI * TAPS + ((long)co * CI + ci) * TAPS + tap];
      if (scale) v *= scale[conv * CO_SRC + co];
    }
    dst[i] = (f16)v;
  }
}

// ---------------- img NCHW f32 -> padded NHWC f16 ----------------
__global__ void img_trans_kernel(const float* __restrict__ src, f16* __restrict__ dst) {
  __shared__ float tile[32][33];
  int tx = threadIdx.x & 31, ty = threadIdx.x >> 5;
  int wt = blockIdx.x % 3, ct = blockIdx.x / 3;
  int h = blockIdx.y, n = blockIdx.z;
  int w0 = wt * 32, c0 = ct * 32;
  #pragma unroll
  for (int i = 0; i < 4; ++i) {
    int cl = ty + i * 8;
    int w = w0 + tx;
    float v = 0.f;
    if (w < WW) v = src[((long)(n * CINF + c0 + cl) * HH + h) * WW + w];
    tile[cl][tx] = v;
  }
  __syncthreads();
  #pragma unroll
  for (int i = 0; i < 4; ++i) {
    int wl = ty + i * 8;
    int w = w0 + wl;
    if (w < WW)
      dst[((long)((n * PH + h + 1) * PW + (w + 1))) * CINF + c0 + tx] = (f16)tile[tx][wl];
  }
}

// ---------------- SE gate ----------------
__global__ void se_gate_kernel(const float* __restrict__ intr,
                               const float* __restrict__ w1, const float* __restrict__ b1,
                               const float* __restrict__ w2, const float* __restrict__ b2,
                               const float* __restrict__ rw, const float* __restrict__ rb,
                               const float* __restrict__ ew, const float* __restrict__ eb,
                               float* __restrict__ gate) {
  __shared__ float sps;
  __shared__ float h1[MIDC];
  __shared__ float h2[MIDC];
  __shared__ float tt[MIDC];
  int n = blockIdx.x, c = threadIdx.x;
  if (c == 0) {
    float a[4][8];
    for (int i = 0; i < 4; ++i)
      for (int j = 0; j < 4; ++j) {
        a[i][j] = intr[n * 16 + i * 4 + j];
        a[i][4 + j] = (i == j) ? 1.f : 0.f;
      }
    for (int col = 0; col < 4; ++col) {
      int piv = col;
      for (int r2 = col + 1; r2 < 4; ++r2)
        if (fabsf(a[r2][col]) > fabsf(a[piv][col])) piv = r2;
      if (piv != col)
        for (int j = 0; j < 8; ++j) { float tv = a[col][j]; a[col][j] = a[piv][j]; a[piv][j] = tv; }
      float invp = 1.f / a[col][col];
      for (int j = 0; j < 8; ++j) a[col][j] *= invp;
      for (int r2 = 0; r2 < 4; ++r2)
        if (r2 != col) {
          float f = a[r2][col];
          for (int j = 0; j < 8; ++j) a[r2][j] -= f * a[col][j];
        }
    }
    float i00 = a[0][4], i11 = a[1][5];
    sps = sqrtf(i00 * i00 + i11 * i11) * 1000.f;
  }
  __syncthreads();
  float sp = sps;
  h1[c] = fmaxf(sp * w1[c] + b1[c], 0.f);
  __syncthreads();
  float acc = b2[c];
  for (int j = 0; j < MIDC; ++j) acc += h1[j] * w2[j * MIDC + c];
  h2[c] = acc;
  __syncthreads();
  acc = rb[c];
  for (int j = 0; j < MIDC; ++j) acc += rw[c * MIDC + j] * h2[j];
  tt[c] = fmaxf(acc, 0.f);
  __syncthreads();
  acc = eb[c];
  for (int j = 0; j < MIDC; ++j) acc += ew[c * MIDC + j] * tt[j];
  gate[n * MIDC + c] = 1.f / (1.f + expf(-acc));
}

// ---------------- MFMA implicit-GEMM conv, m97 structure (A AND B via LDS) ----------------
// Tile 128co x 64pos, 4 waves (2x2), wave 64co x 32pos.
// Per chunk (64 ci x tap): A = 16KB weights (2 groups) via global_load_lds, shared by
// wn-wave pairs; B = 8KB activations via global_load_lds (XOR-swizzled). Both read back
// with lane-linear ds_read_b128. LDS 2 x 24KB double-buffer. This removes the per-wave
// global weight stream that was serializing ~L2-latency chains inside each barrier
// interval (round-1 post-mortem: VGPR=52 proved the af double-buffer never lived in regs).
// MODE 0: relu(acc+b)*gate   MODE 1: relu(acc+b)   MODE 2: relu(acc+b+res)   MODE 3: acc+b -> f32
template<int MODE, int CIN_T, int TAPS>
__global__ __launch_bounds__(256, 2)
void conv_mfma(const f16* __restrict__ X, const f16* __restrict__ Wf,
               const float* __restrict__ bias, const float* __restrict__ gate,
               const f16* __restrict__ res, f16* __restrict__ Yf16,
               float* __restrict__ Yf32, int co_tiles) {
  constexpr int KST = CIN_T / 32;
  constexpr int CPT = CIN_T / 64;
  constexpr int NCH = TAPS * CPT;
  constexpr int LCPT = (CPT == 8) ? 3 : 2;
  constexpr long GSTR = (long)TAPS * KST * 4096;   // bytes per weight group
  __shared__ __align__(16) char S[49152];          // 2 x (16KB A + 8KB B)

  const int t = threadIdx.x;
  const int wv = t >> 6, ln = t & 63, lm = ln & 15, quad = ln >> 4;
  const int wm = wv >> 1, wn = wv & 1;
  const int bid = blockIdx.x;
  const int co_tile = bid % co_tiles;
  const int ptile = bid / co_tiles;
  const int cam = ptile / PT_PER_CAM;
  const int pbase = (ptile % PT_PER_CAM) * PTILE;

  // B DMA setup: 2 instrs/wave, each covers 8 rows x 8 phys chunks
  const f16* gB[2]; int ldsoffB[2];
  const int clog = (ln & 7) ^ (ln >> 3);
  #pragma unroll
  for (int j = 0; j < 2; ++j) {
    int reg = j * 4 + wv;
    int r = reg * 8 + (ln >> 3);
    int pos = pbase + r;
    int hh = pos / WW, w2 = pos - hh * WW;
    gB[j] = X + ((long)((cam * PH + hh + 1) * PW + (w2 + 1))) * CIN_T + clog * 8;
    ldsoffB[j] = 16384 + reg * 1024;
  }

  // lane-constant bf addressing (bytes, within B region)
  const int base_l = (wn * 32 + lm) * 128;
  const int sx0 = ((0 * 4 + quad) ^ (lm & 7)) * 16;
  const int sx1 = ((1 * 4 + quad) ^ (lm & 7)) * 16;

  f32x4 acc[4][2];
  #pragma unroll
  for (int mi = 0; mi < 4; ++mi)
    #pragma unroll
    for (int ni = 0; ni < 2; ++ni)
      #pragma unroll
      for (int r = 0; r < 4; ++r) acc[mi][ni][r] = 0.f;

  auto choff = [&](int c) -> long {
    long off = 0;
    if (TAPS == 9) {
      int tp = c >> LCPT;
      int dy = tp / 3 - 1, dx = tp % 3 - 1;
      off = (long)(dy * PW + dx) * CIN_T;
    }
    return off + (long)(c & (CPT - 1)) * 64;
  };
  // stage one chunk's A (16KB: group0 8KB then group1 8KB) into buffer bsel
  auto stageA = [&](int bsel, int c) {
    const char* sb = (const char*)Wf + (long)c * 8192 + (long)ln * 16;
    char* db = S + bsel * 24576;
    #pragma unroll
    for (int j = 0; j < 4; ++j) {
      int seg = j * 4 + wv;                       // 0..15 (1KB segments)
      long gb = (long)(co_tile * 2 + (seg >> 3)) * GSTR;
      gl_lds16(sb + gb + (seg & 7) * 1024, db + seg * 1024);
    }
  };
  auto stageB = [&](int bsel, long curf) {
    #pragma unroll
    for (int j = 0; j < 2; ++j)
      gl_lds16(gB[j] + curf, S + bsel * 24576 + ldsoffB[j]);
  };
  auto compute = [&](int bsel) {
    const char* ab = S + bsel * 24576 + wm * 8192 + ln * 16;
    const char* bb = S + bsel * 24576 + 16384 + base_l;
    #pragma unroll
    for (int s = 0; s < 2; ++s) {
      f16x8 af[4];
      #pragma unroll
      for (int mi = 0; mi < 4; ++mi)
        af[mi] = *(const f16x8*)(ab + s * 4096 + mi * 1024);
      f16x8 bf[2];
      int sx = s ? sx1 : sx0;
      #pragma unroll
      for (int ni = 0; ni < 2; ++ni)
        bf[ni] = *(const f16x8*)(bb + ni * 2048 + sx);
      #pragma unroll
      for (int mi = 0; mi < 4; ++mi)
        #pragma unroll
        for (int ni = 0; ni < 2; ++ni)
          acc[mi][ni] = __builtin_amdgcn_mfma_f32_16x16x32_f16(af[mi], bf[ni], acc[mi][ni], 0, 0, 0);
    }
  };

  stageA(0, 0);
  stageB(0, choff(0));
  __syncthreads();

  #pragma unroll 1
  for (int c = 0; c < NCH; ++c) {
    int cur = c & 1;
    if (c + 1 < NCH) { stageA(cur ^ 1, c + 1); stageB(cur ^ 1, choff(c + 1)); }
    compute(cur);
    __syncthreads();
  }

  // ---- epilogue: direct stores from acc ----
  float4 b4[4], g4[4];
  bool skip[4];
  #pragma unroll
  for (int mi = 0; mi < 4; ++mi) {
    int co_l = wm * 64 + mi * 16 + quad * 4;
    int co_g = co_tile * 128 + co_l;
    skip[mi] = (MODE == 3) && (co_l >= DB);
    if (!skip[mi]) b4[mi] = *(const float4*)(bias + co_g);
    if (MODE == 0) g4[mi] = *(const float4*)(gate + cam * MIDC + co_g);
  }
  #pragma unroll
  for (int ni = 0; ni < 2; ++ni) {
    int pos = pbase + wn * 32 + ni * 16 + lm;
    long ob;
    if (MODE == 3) ob = ((long)(cam * NPOS + pos)) * DB;
    else {
      int hh = pos / WW, w2 = pos - hh * WW;
      ob = ((long)((cam * PH + hh + 1) * PW + (w2 + 1))) * MIDC + co_tile * 128;
    }
    #pragma unroll
    for (int mi = 0; mi < 4; ++mi) {
      if (skip[mi]) continue;
      int co_l = wm * 64 + mi * 16 + quad * 4;
      float v[4];
      #pragma unroll
      for (int r = 0; r < 4; ++r) {
        float y = acc[mi][ni][r];
        y += ((float*)&b4[mi])[r];
        if (MODE == 0) y = fmaxf(y, 0.f) * ((float*)&g4[mi])[r];
        else if (MODE == 1) y = fmaxf(y, 0.f);
        v[r] = y;
      }
      if (MODE == 3) {
        float4 o; o.x = v[0]; o.y = v[1]; o.z = v[2]; o.w = v[3];
        *(float4*)(Yf32 + ob + co_l) = o;
      } else if (MODE == 2) {
        f16x4 rv = *(const f16x4*)(res + ob + co_l);
        f16x4 o;
        #pragma unroll
        for (int r = 0; r < 4; ++r) o[r] = (f16)fmaxf(v[r] + (float)rv[r], 0.f);
        *(f16x4*)(Yf16 + ob + co_l) = o;
      } else {
        f16x4 o;
        #pragma unroll
        for (int r = 0; r < 4; ++r) o[r] = (f16)v[r];
        *(f16x4*)(Yf16 + ob + co_l) = o;
      }
    }
  }
}

// ---------------- softmax over 112 bins, one wave per position ----------------
__global__ void softmax_kernel(const float* __restrict__ L, float* __restrict__ dp) {
  int wid = (int)(((long)blockIdx.x * blockDim.x + threadIdx.x) >> 6);
  int lane = threadIdx.x & 63;
  if (wid >= NCAM * NPOS) return;
  const float* lp = L + (long)wid * DB;
  float v0 = -1e30f, v1 = -1e30f;
  if (lane < 56) { v0 = lp[lane * 2]; v1 = lp[lane * 2 + 1]; }
  float m = fmaxf(v0, v1);
  #pragma unroll
  for (int o = 32; o; o >>= 1) m = fmaxf(m, __shfl_xor(m, o));
  float e0 = 0.f, e1 = 0.f;
  if (lane < 56) { e0 = __expf(v0 - m); e1 = __expf(v1 - m); }
  float ssum = e0 + e1;
  #pragma unroll
  for (int o = 32; o; o >>= 1) ssum += __shfl_xor(ssum, o);
  float inv = 1.f / ssum;
  if (lane < 56) {
    float2 r; r.x = e0 * inv; r.y = e1 * inv;
    *(float2*)(dp + (long)wid * DB + lane * 2) = r;
  }
}

// ---------------- trilinear grid sample + camera sum + normalize ----------------
__global__ void sample_kernel(const float* __restrict__ grid, const float* __restrict__ dp,
                              float* __restrict__ out) {
  int v = blockIdx.x * blockDim.x + threadIdx.x;
  if (v >= 128 * 128 * 16) return;
  int vz = v & 15, vy = (v >> 4) & 127, vx = v >> 11;
  float agg = 0.f, msk = 0.f;
  #pragma unroll 1
  for (int n = 0; n < NCAM; ++n) {
    long gb = ((long)((n * 128 + vx) * 128 + vy) * 16 + vz) * 3;
    float gx = grid[gb], gy = grid[gb + 1], gz = grid[gb + 2];
    float ix = ((gx + 1.f) * (float)WW - 1.f) * 0.5f;
    float iy = ((gy + 1.f) * (float)HH - 1.f) * 0.5f;
    float iz = ((gz + 1.f) * (float)DB - 1.f) * 0.5f;
    float xf = floorf(ix), yf = floorf(iy), zf = floorf(iz);
    float fx = ix - xf, fy = iy - yf, fz = iz - zf;
    int x0 = (int)xf, y0 = (int)yf, z0 = (int)zf;
    float wxa[2] = {1.f - fx, fx};
    float wya[2] = {1.f - fy, fy};
    float wza[2] = {1.f - fz, fz};
    #pragma unroll
    for (int dy2 = 0; dy2 < 2; ++dy2) {
      int y = y0 + dy2;
      bool vyb = (y >= 0) && (y < HH);
      int yc = y < 0 ? 0 : (y > HH - 1 ? HH - 1 : y);
      #pragma unroll
      for (int dx2 = 0; dx2 < 2; ++dx2) {
        int x = x0 + dx2;
        bool vxb = (x >= 0) && (x < WW);
        int xc = x < 0 ? 0 : (x > WW - 1 ? WW - 1 : x);
        float wxy = wxa[dx2] * wya[dy2];
        const float* base = dp + ((long)((n * HH + yc) * WW + xc)) * DB;
        #pragma unroll
        for (int dz2 = 0; dz2 < 2; ++dz2) {
          int z = z0 + dz2;
          bool vzb = (z >= 0) && (z < DB);
          int zc = z < 0 ? 0 : (z > DB - 1 ? DB - 1 : z);
          float wgt = wxy * wza[dz2];
          if (vxb && vyb && vzb) {
            msk += wgt;
            agg += wgt * base[zc];
          }
        }
      }
    }
  }
  out[v] = (msk > 0.f) ? (agg / msk) : agg;
}

extern "C" void kernel_launch(void* const* d_in, const int* in_sizes, int n_in,
                              void* d_out, int out_size, void* d_ws, size_t ws_size,
                              hipStream_t stream) {
  const float* img   = (const float*)d_in[0];
  const float* intr  = (const float*)d_in[1];
  const float* grid  = (const float*)d_in[2];
  const float* red_w = (const float*)d_in[3];
  const float* red_s = (const float*)d_in[4];
  const float* red_b = (const float*)d_in[5];
  const float* w1    = (const float*)d_in[6];
  const float* b1    = (const float*)d_in[7];
  const float* w2    = (const float*)d_in[8];
  const float* b2    = (const float*)d_in[9];
  const float* rw    = (const float*)d_in[10];
  const float* rb    = (const float*)d_in[11];
  const float* ew    = (const float*)d_in[12];
  const float* eb    = (const float*)d_in[13];
  const float* bb_w  = (const float*)d_in[14];
  const float* bb_s  = (const float*)d_in[15];
  const float* bb_b  = (const float*)d_in[16];
  const float* dp_w  = (const float*)d_in[17];
  const float* dp_b  = (const float*)d_in[18];
  float* out = (float*)d_out;

  char* ws = (char*)d_ws;
  float* gate = (float*)(ws + O_GATE);
  f16* wfred  = (f16*)(ws + O_WFRED);
  f16* wfbb   = (f16*)(ws + O_WFBB);
  f16* wfdp   = (f16*)(ws + O_WFDP);
  f16* xp0    = (f16*)(ws + O_XP0);
  f16* X1     = (f16*)(ws + O_X1);
  f16* X2     = (f16*)(ws + O_X2);
  f16* X3     = (f16*)(ws + O_X3);
  float* Lg   = (float*)(ws + O_LOG);
  float* dpb  = (float*)(ws + O_DP);

  halo_zero_kernel<<<915, 256, 0, stream>>>(xp0, X1, X2, X3);
  {
    long per = 4L * 9 * 16 * 2048, total = per;
    wfrag_kernel<<<2048, 256, 0, stream>>>(red_w, red_s, wfred, 1, 4, 9, 512, 256, per, total);
  }
  {
    long per = 4L * 9 * 8 * 2048, total = 6 * per;
    wfrag_kernel<<<4096, 256, 0, stream>>>(bb_w, bb_s, wfbb, 6, 4, 9, 256, 256, per, total);
  }
  {
    long per = 2L * 1 * 8 * 2048, total = per;
    wfrag_kernel<<<128, 256, 0, stream>>>(dp_w, nullptr, wfdp, 1, 2, 1, 256, 112, per, total);
  }
  img_trans_kernel<<<dim3(48, 32, 6), 256, 0, stream>>>(img, xp0);
  se_gate_kernel<<<6, 256, 0, stream>>>(intr, w1, b1, w2, b2, rw, rb, ew, eb, gate);

  const long WCH = 4L * 9 * 8 * 2048;  // per-conv fragment-weight stride (f16)

  conv_mfma<0, 512, 9><<<528, 256, 0, stream>>>(xp0, wfred, red_b, gate, nullptr, X1, nullptr, 2);

  conv_mfma<1, 256, 9><<<528, 256, 0, stream>>>(X1, wfbb + 0 * WCH, bb_b + 0 * 256, nullptr, nullptr, X2, nullptr, 2);
  conv_mfma<2, 256, 9><<<528, 256, 0, stream>>>(X2, wfbb + 1 * WCH, bb_b + 1 * 256, nullptr, X1, X3, nullptr, 2);
  conv_mfma<1, 256, 9><<<528, 256, 0, stream>>>(X3, wfbb + 2 * WCH, bb_b + 2 * 256, nullptr, nullptr, X2, nullptr, 2);
  conv_mfma<2, 256, 9><<<528, 256, 0, stream>>>(X2, wfbb + 3 * WCH, bb_b + 3 * 256, nullptr, X3, X1, nullptr, 2);
  conv_mfma<1, 256, 9><<<528, 256, 0, stream>>>(X1, wfbb + 4 * WCH, bb_b + 4 * 256, nullptr, nullptr, X2, nullptr, 2);
  conv_mfma<2, 256, 9><<<528, 256, 0, stream>>>(X2, wfbb + 5 * WCH, bb_b + 5 * 256, nullptr, X1, X3, nullptr, 2);

  conv_mfma<3, 256, 1><<<264, 256, 0, stream>>>(X3, wfdp, dp_b, nullptr, nullptr, nullptr, Lg, 1);

  softmax_kernel<<<4224, 256, 0, stream>>>(Lg, dpb);
  sample_kernel<<<1024, 256, 0, stream>>>(grid, dpb, out);
}